// Round 23
// baseline (64.502 us; speedup 1.0000x reference)
//
#include <hip/hip_runtime.h>
#include <stdint.h>
#include <math.h>

using short8   = __attribute__((ext_vector_type(8))) short;
using ushort4v = __attribute__((ext_vector_type(4))) unsigned short;
using f32x4    = __attribute__((ext_vector_type(4))) float;
using uint4v   = __attribute__((ext_vector_type(4))) unsigned int;
using uint2v   = __attribute__((ext_vector_type(2))) unsigned int;

#define B_ 2
#define S_ 64
#define K_ 64
#define D_ 256
#define C_ 32
#define N_ 4096  /* S_*K_ */
#define LOG2E 1.4426950408889634f

__device__ __forceinline__ float b2f(unsigned short u) {
    unsigned int v = ((unsigned int)u) << 16;
    return __builtin_bit_cast(float, v);
}
__device__ __forceinline__ unsigned short f2b(float f) {   // RNE f32->bf16
    unsigned int x = __builtin_bit_cast(unsigned int, f);
    x += 0x7fffu + ((x >> 16) & 1u);
    return (unsigned short)(x >> 16);
}
// pack two f32 -> bf16x2 (a low, b high), RNE, pure ALU (m240)
__device__ __forceinline__ unsigned int pk2(float a, float b) {
    unsigned int xa = __builtin_bit_cast(unsigned int, a);
    unsigned int xb = __builtin_bit_cast(unsigned int, b);
    xa += 0x7fffu + ((xa >> 16) & 1u);
    xb += 0x7fffu + ((xb >> 16) & 1u);
    return (xa >> 16) | (xb & 0xffff0000u);
}
// load 8 f32 (scaled), produce hi/lo split-bf16 fragments
__device__ __forceinline__ void cvt8s(const float* p, float s, short8& hi, short8& lo) {
    f32x4 a = *(const f32x4*)p;
    f32x4 c = *(const f32x4*)(p + 4);
#pragma unroll
    for (int e = 0; e < 4; ++e) {
        float v0 = a[e] * s;
        unsigned short h0 = f2b(v0);
        hi[e] = (short)h0; lo[e] = (short)f2b(v0 - b2f(h0));
        float v1 = c[e] * s;
        unsigned short h1 = f2b(v1);
        hi[e + 4] = (short)h1; lo[e + 4] = (short)f2b(v1 - b2f(h1));
    }
}
__device__ __forceinline__ void cvt8h(const float* p, short8& hi) {
    f32x4 a = *(const f32x4*)p;
    f32x4 c = *(const f32x4*)(p + 4);
#pragma unroll
    for (int e = 0; e < 4; ++e) {
        hi[e]     = (short)f2b(a[e]);
        hi[e + 4] = (short)f2b(c[e]);
    }
}

// ---------------------------------------------------------------------------
// Kernel 1: QKV projections, 8-wave, W converted INLINE (wcvt kernel
// eliminated: f32 W bytes == bf16 hi+lo plane bytes, only VALU cost; Q
// weights/bias scaled by log2e here). 512 blocks x 512 threads.
// Q,K [B][N][C] hi/lo; V chunk-interleaved [B][N/32][D*32] slot-permuted
// + XOR-swizzled (o ^= (d&7)<<4).
// ---------------------------------------------------------------------------
__global__ __launch_bounds__(512) void qkv_kernel(
    const float* __restrict__ x,
    const float* __restrict__ Wq, const float* __restrict__ bq,
    const float* __restrict__ Wk, const float* __restrict__ bk,
    const float* __restrict__ Wv, const float* __restrict__ bv,
    unsigned short* __restrict__ Qh, unsigned short* __restrict__ Ql,
    unsigned short* __restrict__ Kh, unsigned short* __restrict__ Kl,
    unsigned short* __restrict__ Vm)
{
    __shared__ unsigned short lxh[16 * 256];   // [tok][d] bf16-hi, swizzled
    __shared__ unsigned short lxl[16 * 256];   // bf16-lo

    int tid = threadIdx.x;
    int bid = blockIdx.x;
    int b  = bid >> 8;
    int n0 = (bid & 255) << 4;

    {
        int tt = tid >> 5, m = tid & 31;       // token, 8-f32 granule
        int n = n0 + tt;
        int s = n & 63, kk = n >> 6;
        const float* xr = x + (((size_t)(b * S_ + s)) * K_ + kk) * D_ + m * 8;
        short8 h8, l8;
        cvt8s(xr, 1.0f, h8, l8);
        int sw = ((m ^ (tt & 7)) << 3);
        *(short8*)(lxh + tt * 256 + sw) = h8;
        *(short8*)(lxl + tt * 256 + sw) = l8;
    }
    __syncthreads();

    int wave = tid >> 6, lane = tid & 63;
    int col = lane & 15, g = lane >> 4;

    if (wave < 4) {                            // Q/K: split-bf16 3-chain
        int ct = wave;                         // 0..3
        bool isQ = (ct < 2);
        int row = (isQ ? ct * 16 : (ct - 2) * 16) + col;   // 0..31 in its W
        const float* Wf = isQ ? Wq : Wk;
        const float* wrowf = Wf + (size_t)row * 256;
        float wscale = isQ ? LOG2E : 1.0f;
        f32x4 acc = {0.f, 0.f, 0.f, 0.f};
#pragma unroll
        for (int dc = 0; dc < 8; ++dc) {
            int sw = (((dc * 4 + g) ^ (col & 7)) << 3);
            short8 xh8 = *(const short8*)(lxh + col * 256 + sw);
            short8 xl8 = *(const short8*)(lxl + col * 256 + sw);
            short8 wh8, wl8;
            cvt8s(wrowf + dc * 32 + g * 8, wscale, wh8, wl8);
            acc = __builtin_amdgcn_mfma_f32_16x16x32_bf16(xl8, wh8, acc, 0, 0, 0);
            acc = __builtin_amdgcn_mfma_f32_16x16x32_bf16(xh8, wl8, acc, 0, 0, 0);
            acc = __builtin_amdgcn_mfma_f32_16x16x32_bf16(xh8, wh8, acc, 0, 0, 0);
        }
        float bb = isQ ? bq[row] * LOG2E : bk[row];
        unsigned short* Th = isQ ? Qh : Kh;
        unsigned short* Tl = isQ ? Ql : Kl;
        int c0 = (ct & 1) * 16;
#pragma unroll
        for (int r = 0; r < 4; ++r) {
            int tok = n0 + g * 4 + r;
            float v = acc[r] + bb;
            unsigned short hh = f2b(v);
            size_t idx = ((size_t)b * N_ + tok) * C_ + c0 + col;
            Th[idx] = hh;
            Tl[idx] = f2b(v - b2f(hh));
        }
    } else {                                   // V: single bf16, 4 tiles
        int i = wave - 4;
#pragma unroll
        for (int k = 0; k < 4; ++k) {
            int ct = 4 + i + 4 * k;            // 4..19
            int c0 = ct * 16 - 64;             // V out-channel base 0..240
            const float* wrowf = Wv + (size_t)(c0 + col) * 256;
            f32x4 acc = {0.f, 0.f, 0.f, 0.f};
#pragma unroll
            for (int dc = 0; dc < 8; ++dc) {
                int sw = (((dc * 4 + g) ^ (col & 7)) << 3);
                short8 xh8 = *(const short8*)(lxh + col * 256 + sw);
                short8 wh8;
                cvt8h(wrowf + dc * 32 + g * 8, wh8);
                acc = __builtin_amdgcn_mfma_f32_16x16x32_bf16(xh8, wh8, acc, 0, 0, 0);
            }
            float bb = bv[c0 + col];
            ushort4v st;
#pragma unroll
            for (int r = 0; r < 4; ++r) st[r] = f2b(acc[r] + bb);
            int tok0 = n0 + g * 4;
            int s0 = 8 * g + ((n0 & 16) >> 2); // slot-permuted in-chunk pos
            int d_ch = c0 + col;
            int o = d_ch * 64 + s0 * 2;        // byte offset within 16KB chunk
            o ^= (d_ch & 7) << 4;              // bank-swizzle (8B-run safe)
            size_t vbyteoff = ((size_t)b * (N_ / 32) + (tok0 >> 5)) * (D_ * 32 * 2)
                            + (size_t)o;
            *(ushort4v*)((char*)Vm + vbyteoff) = st;
        }
    }
}

// ---------------------------------------------------------------------------
// Kernel 2: flash attention — EXACT R21 anchor (62.8us): 16 waves, quartered
// QK role, reg-staged V with T14 split, skewed P-exchange, bf16 O dump,
// setprio, __syncthreads barrier (R22's no-vmcnt barrier was neutral: the
// stage value's data dependence forces the vmcnt wait anyway).
// ---------------------------------------------------------------------------
__global__ __launch_bounds__(1024, 4) void attn_kernel(
    const unsigned short* __restrict__ Qh, const unsigned short* __restrict__ Ql,
    const unsigned short* __restrict__ Kh, const unsigned short* __restrict__ Kl,
    const unsigned short* __restrict__ Vm,
    unsigned short* __restrict__ O_bf16, float* __restrict__ lsum_part)
{
    __shared__ __align__(16) char vlds[2][16384];   // V chunk double-buffer
    __shared__ __align__(16) char plds[2 * 8192];   // P exchange double-buffer

    int tid  = threadIdx.x;
    int wave = tid >> 6;          // 0..15
    int lane = tid & 63;
    int col = lane & 15, g = lane >> 4;
    int qq = wave >> 2;           // q-quarter 0..3
    int dq = wave & 3;            // d-quarter 0..3
    int kh = dq & 1;              // produced key-half
    int qs_own = dq >> 1;         // produced q-subtile
    int tid16 = tid * 16;
    int lane16 = lane * 16;

    int bid = blockIdx.x;
    int x7 = bid & 7;
    int b  = x7 >> 2;
    int ks = x7 & 3;
    int qt = bid >> 3;            // 0..31 (q-tile within batch)
    int q0 = qt * 128 + qq * 32;
    int jbase = ks * (N_ / 4);

    // Q fragments for OWN produced subtile only
    size_t qoff = ((size_t)b * N_ + q0 + qs_own * 16 + col) * C_ + g * 8;
    short8 qfh = *(const short8*)(Qh + qoff);
    short8 qfl = *(const short8*)(Ql + qoff);

    f32x4 acc[2][4];
#pragma unroll
    for (int qs = 0; qs < 2; ++qs)
#pragma unroll
        for (int dt = 0; dt < 4; ++dt) acc[qs][dt] = (f32x4){0.f, 0.f, 0.f, 0.f};
    float l_run = 0.f;

    const unsigned short* kbh = Kh + (size_t)b * N_ * C_;
    const unsigned short* kbl = Kl + (size_t)b * N_ * C_;
    const char* vbyte = (const char*)Vm + (size_t)b * ((size_t)N_ * D_ * 2);

    auto kaddr = [&](int it) {
        return (size_t)(jbase + it * 32 + kh * 16 + col) * C_ + g * 8;
    };

    // lane-constant swizzled ds_read offset for V fragments (d-quarter dq)
    unsigned vro = (unsigned)(((dq * 64 + col) * 64 + g * 16) ^ ((col & 7) << 4));
    int st = qq * 2 + qs_own;
    char* pmy = plds + st * 1024 + lane16 + kh * 8;       // own 8B publish slot
    const char* pr0 = plds + (qq * 2) * 1024 + lane16;     // subtile 0 read
    const char* pr1 = plds + (qq * 2 + 1) * 1024 + lane16; // subtile 1 read

    // ---- prologue: stage V(0); K(0)->A, K(1)->B; QK(0) -> plds buf0 ----
    {
        const char* vsrc = vbyte + (size_t)(ks * 32) * 16384 + tid16;
        *(f32x4*)(vlds[0] + tid16) = *(const f32x4*)(vsrc);
    }
    short8 khA = *(const short8*)(kbh + kaddr(0));
    short8 klA = *(const short8*)(kbl + kaddr(0));
    short8 khB = *(const short8*)(kbh + kaddr(1));
    short8 klB = *(const short8*)(kbl + kaddr(1));
    {
        f32x4 z = {0.f, 0.f, 0.f, 0.f};
        f32x4 sa = __builtin_amdgcn_mfma_f32_16x16x32_bf16(klA, qfh, z, 0, 0, 0);
        sa = __builtin_amdgcn_mfma_f32_16x16x32_bf16(khA, qfl, sa, 0, 0, 0);
        sa = __builtin_amdgcn_mfma_f32_16x16x32_bf16(khA, qfh, sa, 0, 0, 0);
        float pa[4];
#pragma unroll
        for (int r = 0; r < 4; ++r) pa[r] = exp2f(sa[r]);
        l_run += (pa[0] + pa[1]) + (pa[2] + pa[3]);
        uint2v uo;
        uo[0] = pk2(pa[0], pa[1]); uo[1] = pk2(pa[2], pa[3]);
        *(uint2v*)(pmy) = uo;   // buffer 0
    }
    __syncthreads();

    // phase IT: stage V(IT+1) (issue early / ds_write late), prefetch
    // K(IT+2), QK(IT+1) own quarter (CUR set), PV(IT) from plds/vlds[IT&1],
    // publish P+V, barrier.
#define ATTN_PHASE(IT, CKH, CKL, NKH, NKL)                                       \
    {                                                                            \
        int itn_ = (IT) + 1;                                                     \
        int itk_ = (IT) + 2;  /* may run past end: wrap-free, discarded */       \
        const char* vsrc_ = vbyte + (size_t)(ks * 32 + itn_) * 16384 + tid16;    \
        f32x4 stg_ = *(const f32x4*)(vsrc_);                                     \
        NKH = *(const short8*)(kbh + kaddr(itk_));                               \
        NKL = *(const short8*)(kbl + kaddr(itk_));                               \
        __builtin_amdgcn_sched_barrier(0);  /* loads stay issued up here */      \
        f32x4 z_ = {0.f, 0.f, 0.f, 0.f};                                         \
        __builtin_amdgcn_s_setprio(1);                                           \
        f32x4 sa_ = __builtin_amdgcn_mfma_f32_16x16x32_bf16(CKL, qfh, z_, 0, 0, 0); \
        sa_ = __builtin_amdgcn_mfma_f32_16x16x32_bf16(CKH, qfl, sa_, 0, 0, 0);   \
        sa_ = __builtin_amdgcn_mfma_f32_16x16x32_bf16(CKH, qfh, sa_, 0, 0, 0);   \
        __builtin_amdgcn_s_setprio(0);                                           \
        float pa_[4];                                                            \
        _Pragma("unroll")                                                        \
        for (int r = 0; r < 4; ++r) pa_[r] = exp2f(sa_[r]);                      \
        l_run += (pa_[0] + pa_[1]) + (pa_[2] + pa_[3]);                          \
        uint2v uo_;                                                              \
        uo_[0] = pk2(pa_[0], pa_[1]); uo_[1] = pk2(pa_[2], pa_[3]);              \
        int rb_ = (IT) & 1, wb_ = (itn_) & 1;                                    \
        short8 pf0_ = *(const short8*)(pr0 + rb_ * 8192);                        \
        short8 pf1_ = *(const short8*)(pr1 + rb_ * 8192);                        \
        short8 vf_[4];                                                           \
        _Pragma("unroll")                                                        \
        for (int dt = 0; dt < 4; ++dt)                                           \
            vf_[dt] = *(const short8*)(vlds[rb_] + vro + dt * 1024);             \
        __builtin_amdgcn_s_setprio(1);                                           \
        _Pragma("unroll")                                                        \
        for (int dt = 0; dt < 4; ++dt) {                                         \
            acc[0][dt] = __builtin_amdgcn_mfma_f32_16x16x32_bf16(vf_[dt], pf0_, acc[0][dt], 0, 0, 0); \
            acc[1][dt] = __builtin_amdgcn_mfma_f32_16x16x32_bf16(vf_[dt], pf1_, acc[1][dt], 0, 0, 0); \
        }                                                                        \
        __builtin_amdgcn_s_setprio(0);                                           \
        *(uint2v*)(pmy + wb_ * 8192) = uo_;                                      \
        *(f32x4*)(vlds[wb_] + tid16) = stg_;                                     \
        __syncthreads();                                                         \
    }

    for (int it2 = 0; it2 < 15; ++it2) {
        int itA = it2 * 2, itB = itA + 1;
        ATTN_PHASE(itA, khB, klB, khA, klA);
        ATTN_PHASE(itB, khA, klA, khB, klB);
    }
    ATTN_PHASE(30, khB, klB, khA, klA);
#undef ATTN_PHASE

    // epilogue: PV(31) from plds/vlds buffer 1
    {
        short8 pf0 = *(const short8*)(pr0 + 8192);
        short8 pf1 = *(const short8*)(pr1 + 8192);
        short8 vf[4];
#pragma unroll
        for (int dt = 0; dt < 4; ++dt)
            vf[dt] = *(const short8*)(vlds[1] + vro + dt * 1024);
#pragma unroll
        for (int dt = 0; dt < 4; ++dt) {
            acc[0][dt] = __builtin_amdgcn_mfma_f32_16x16x32_bf16(vf[dt], pf0, acc[0][dt], 0, 0, 0);
            acc[1][dt] = __builtin_amdgcn_mfma_f32_16x16x32_bf16(vf[dt], pf1, acc[1][dt], 0, 0, 0);
        }
    }

    // l reduction across the 4 g-groups (own subtile x own key-half)
    l_run += __shfl_xor(l_run, 16); l_run += __shfl_xor(l_run, 32);

    // dump partials as BF16, epi-compatible element layout: w = qq*2+(dq>>1),
    // j = qs*8 + (dq&1)*4 + dt, element = col*16 + g*4 (ushort units).
    unsigned short* op = O_bf16 + (size_t)bid * 32768 + (qq * 2 + (dq >> 1)) * 4096;
#pragma unroll
    for (int qs = 0; qs < 2; ++qs)
#pragma unroll
        for (int dt = 0; dt < 4; ++dt) {
            int j = qs * 8 + (dq & 1) * 4 + dt;
            uint2v uo;
            uo[0] = pk2(acc[qs][dt][0], acc[qs][dt][1]);
            uo[1] = pk2(acc[qs][dt][2], acc[qs][dt][3]);
            *(uint2v*)(op + j * 256 + col * 16 + g * 4) = uo;
        }
    if (g == 0)   // wave owns lsum slot (kh plane, qq, qs_own)
        lsum_part[bid * 256 + kh * 128 + qq * 32 + qs_own * 16 + col] = l_run;
}

// ---------------------------------------------------------------------------
// Kernel 3: epilogue. out[b,s,k,d] = gamma * (sum_ks O)/(sum_ks l) + x.
// O_part bf16 (same element-unit layout); l summed over kh planes.
// ---------------------------------------------------------------------------
__global__ __launch_bounds__(256) void epi_kernel(
    const unsigned short* __restrict__ O_bf16, const float* __restrict__ lsum_part,
    const float* __restrict__ x, const float* __restrict__ gamma_p,
    float* __restrict__ out)
{
    int gid = blockIdx.x * 256 + threadIdx.x;   // 0..524287
    int d  = (gid & 63) * 4;
    int nl = gid >> 6;
    int b  = nl >> 12;
    int n  = nl & (N_ - 1);

    int qt = n >> 7, qq = (n >> 5) & 3, qs = (n >> 4) & 1, col = n & 15;
    int dh = d >> 7, dt = (d >> 4) & 7;
    int w = qq * 2 + dh, j = qs * 8 + dt;
    int boff = w * 4096 + j * 256 + col * 16 + (d & 15);
    int loff = qq * 32 + qs * 16 + col;

    f32x4 acc = {0.f, 0.f, 0.f, 0.f};
    float l = 0.f;
#pragma unroll
    for (int ks = 0; ks < 4; ++ks) {
        int bid = qt * 8 + b * 4 + ks;
        ushort4v p = *(const ushort4v*)(O_bf16 + (size_t)bid * 32768 + boff);
        acc[0] += b2f(p[0]); acc[1] += b2f(p[1]);
        acc[2] += b2f(p[2]); acc[3] += b2f(p[3]);
        l += lsum_part[bid * 256 + loff] + lsum_part[bid * 256 + 128 + loff];
    }
    float scale = gamma_p[0] / l;
    int s = n & 63, kk = n >> 6;
    size_t o = (((size_t)(b * S_ + s)) * K_ + kk) * D_ + d;
    f32x4 xv = *(const f32x4*)(x + o);
    f32x4 ov;
#pragma unroll
    for (int e = 0; e < 4; ++e) ov[e] = acc[e] * scale + xv[e];
    *(f32x4*)(out + o) = ov;
}

extern "C" void kernel_launch(void* const* d_in, const int* in_sizes, int n_in,
                              void* d_out, int out_size, void* d_ws, size_t ws_size,
                              hipStream_t stream) {
    const float* x  = (const float*)d_in[0];
    const float* Wq = (const float*)d_in[1];
    const float* bq = (const float*)d_in[2];
    const float* Wk = (const float*)d_in[3];
    const float* bk = (const float*)d_in[4];
    const float* Wv = (const float*)d_in[5];
    const float* bv = (const float*)d_in[6];
    const float* gm = (const float*)d_in[7];

    char* ws = (char*)d_ws;
    unsigned short* Qh   = (unsigned short*)(ws + 0x100000);      // 512KB
    unsigned short* Ql   = (unsigned short*)(ws + 0x180000);
    unsigned short* Kh   = (unsigned short*)(ws + 0x200000);
    unsigned short* Kl   = (unsigned short*)(ws + 0x280000);
    unsigned short* Vm   = (unsigned short*)(ws + 0x300000);      // 4MB
    unsigned short* Op   = (unsigned short*)(ws + 0x700000);      // 16MB (bf16)
    float*          lp   = (float*)         (ws + 0x2700000);     // 256KB
    float* o = (float*)d_out;

    qkv_kernel<<<512, 512, 0, stream>>>(x, Wq, bq, Wk, bk, Wv, bv,
                                        Qh, Ql, Kh, Kl, Vm);
    attn_kernel<<<256, 1024, 0, stream>>>(Qh, Ql, Kh, Kl, Vm, Op, lp);
    epi_kernel<<<2048, 256, 0, stream>>>(Op, lp, x, gm, o);
}

// Round 24
// 62.826 us; speedup vs baseline: 1.0267x; 1.0267x over previous
//
#include <hip/hip_runtime.h>
#include <stdint.h>
#include <math.h>

using short8   = __attribute__((ext_vector_type(8))) short;
using ushort4v = __attribute__((ext_vector_type(4))) unsigned short;
using f32x4    = __attribute__((ext_vector_type(4))) float;
using uint4v   = __attribute__((ext_vector_type(4))) unsigned int;
using uint2v   = __attribute__((ext_vector_type(2))) unsigned int;

#define B_ 2
#define S_ 64
#define K_ 64
#define D_ 256
#define C_ 32
#define N_ 4096  /* S_*K_ */
#define LOG2E 1.4426950408889634f

__device__ __forceinline__ float b2f(unsigned short u) {
    unsigned int v = ((unsigned int)u) << 16;
    return __builtin_bit_cast(float, v);
}
__device__ __forceinline__ unsigned short f2b(float f) {   // RNE f32->bf16
    unsigned int x = __builtin_bit_cast(unsigned int, f);
    x += 0x7fffu + ((x >> 16) & 1u);
    return (unsigned short)(x >> 16);
}
// pack two f32 -> bf16x2 (a low, b high), RNE, pure ALU (m240)
__device__ __forceinline__ unsigned int pk2(float a, float b) {
    unsigned int xa = __builtin_bit_cast(unsigned int, a);
    unsigned int xb = __builtin_bit_cast(unsigned int, b);
    xa += 0x7fffu + ((xa >> 16) & 1u);
    xb += 0x7fffu + ((xb >> 16) & 1u);
    return (xa >> 16) | (xb & 0xffff0000u);
}

// ---------------------------------------------------------------------------
// Kernel 0: W/bias pre-convert. oc 0-31 Q (x log2e), 32-63 K, 64-319 V.
// (R23 lesson: inlining this into qkv re-converts W per block, 512x -- keep
// the dedicated kernel.)
// ---------------------------------------------------------------------------
__global__ __launch_bounds__(256) void wcvt_kernel(
    const float* __restrict__ Wq, const float* __restrict__ bq,
    const float* __restrict__ Wk, const float* __restrict__ bk,
    const float* __restrict__ Wv, const float* __restrict__ bv,
    unsigned short* __restrict__ Wh, unsigned short* __restrict__ Wl,
    float* __restrict__ bcat)
{
    int oc = blockIdx.x;            // 0..319
    int d  = threadIdx.x;           // 0..255
    float w;
    if (oc < 32)       w = Wq[oc * 256 + d] * LOG2E;
    else if (oc < 64)  w = Wk[(oc - 32) * 256 + d];
    else               w = Wv[(oc - 64) * 256 + d];
    unsigned short h = f2b(w);
    Wh[oc * 256 + d] = h;
    Wl[oc * 256 + d] = f2b(w - b2f(h));
    if (d == 0) {
        float bb;
        if (oc < 32)      bb = bq[oc] * LOG2E;
        else if (oc < 64) bb = bk[oc - 32];
        else              bb = bv[oc - 64];
        bcat[oc] = bb;
    }
}

// ---------------------------------------------------------------------------
// Kernel 1: QKV projections, 8-wave (verified R20/R21). 512 blocks x 512
// threads. Q,K [B][N][C] hi/lo; V chunk-interleaved [B][N/32][D*32]
// slot-permuted + XOR-swizzled (o ^= (d&7)<<4).
// ---------------------------------------------------------------------------
__global__ __launch_bounds__(512) void qkv_kernel(
    const float* __restrict__ x,
    const unsigned short* __restrict__ Wh, const unsigned short* __restrict__ Wl,
    const float* __restrict__ bcat,
    unsigned short* __restrict__ Qh, unsigned short* __restrict__ Ql,
    unsigned short* __restrict__ Kh, unsigned short* __restrict__ Kl,
    unsigned short* __restrict__ Vm)
{
    __shared__ unsigned short lxh[16 * 256];   // [tok][d] bf16-hi, swizzled
    __shared__ unsigned short lxl[16 * 256];   // bf16-lo

    int tid = threadIdx.x;
    int bid = blockIdx.x;
    int b  = bid >> 8;
    int n0 = (bid & 255) << 4;

    {
        int tt = tid >> 5, m = tid & 31;       // token, 8-f32 granule
        int n = n0 + tt;
        int s = n & 63, kk = n >> 6;
        const float* xr = x + (((size_t)(b * S_ + s)) * K_ + kk) * D_ + m * 8;
        short8 h8, l8;
#pragma unroll
        for (int e = 0; e < 8; ++e) {
            float v = xr[e];
            unsigned short hh = f2b(v);
            h8[e] = (short)hh; l8[e] = (short)f2b(v - b2f(hh));
        }
        int sw = ((m ^ (tt & 7)) << 3);
        *(short8*)(lxh + tt * 256 + sw) = h8;
        *(short8*)(lxl + tt * 256 + sw) = l8;
    }
    __syncthreads();

    int wave = tid >> 6, lane = tid & 63;
    int col = lane & 15, g = lane >> 4;

    if (wave < 4) {                            // Q/K: split-bf16 3-chain
        int ct = wave;                         // 0..3
        int oc0 = ct * 16;
        const unsigned short* whr = Wh + (size_t)(oc0 + col) * 256;
        const unsigned short* wlr = Wl + (size_t)(oc0 + col) * 256;
        f32x4 acc = {0.f, 0.f, 0.f, 0.f};
#pragma unroll
        for (int dc = 0; dc < 8; ++dc) {
            int sw = (((dc * 4 + g) ^ (col & 7)) << 3);
            short8 xh8 = *(const short8*)(lxh + col * 256 + sw);
            short8 xl8 = *(const short8*)(lxl + col * 256 + sw);
            short8 wh8 = *(const short8*)(whr + dc * 32 + g * 8);
            short8 wl8 = *(const short8*)(wlr + dc * 32 + g * 8);
            acc = __builtin_amdgcn_mfma_f32_16x16x32_bf16(xl8, wh8, acc, 0, 0, 0);
            acc = __builtin_amdgcn_mfma_f32_16x16x32_bf16(xh8, wl8, acc, 0, 0, 0);
            acc = __builtin_amdgcn_mfma_f32_16x16x32_bf16(xh8, wh8, acc, 0, 0, 0);
        }
        float bb = bcat[oc0 + col];
        unsigned short* Th = (ct < 2) ? Qh : Kh;
        unsigned short* Tl = (ct < 2) ? Ql : Kl;
        int c0 = (ct & 1) * 16;
#pragma unroll
        for (int r = 0; r < 4; ++r) {
            int tok = n0 + g * 4 + r;
            float v = acc[r] + bb;
            unsigned short hh = f2b(v);
            size_t idx = ((size_t)b * N_ + tok) * C_ + c0 + col;
            Th[idx] = hh;
            Tl[idx] = f2b(v - b2f(hh));
        }
    } else {                                   // V: single bf16, 4 tiles
        int i = wave - 4;
#pragma unroll
        for (int k = 0; k < 4; ++k) {
            int ct = 4 + i + 4 * k;            // 4..19
            int oc0 = ct * 16;
            const unsigned short* whr = Wh + (size_t)(oc0 + col) * 256;
            f32x4 acc = {0.f, 0.f, 0.f, 0.f};
#pragma unroll
            for (int dc = 0; dc < 8; ++dc) {
                int sw = (((dc * 4 + g) ^ (col & 7)) << 3);
                short8 xh8 = *(const short8*)(lxh + col * 256 + sw);
                short8 wh8 = *(const short8*)(whr + dc * 32 + g * 8);
                acc = __builtin_amdgcn_mfma_f32_16x16x32_bf16(xh8, wh8, acc, 0, 0, 0);
            }
            float bb = bcat[oc0 + col];
            int c0 = oc0 - 64;
            ushort4v st;
#pragma unroll
            for (int r = 0; r < 4; ++r) st[r] = f2b(acc[r] + bb);
            int tok0 = n0 + g * 4;
            int s0 = 8 * g + ((n0 & 16) >> 2); // slot-permuted in-chunk pos
            int d_ch = c0 + col;
            int o = d_ch * 64 + s0 * 2;        // byte offset within 16KB chunk
            o ^= (d_ch & 7) << 4;              // bank-swizzle (8B-run safe)
            size_t vbyteoff = ((size_t)b * (N_ / 32) + (tok0 >> 5)) * (D_ * 32 * 2)
                            + (size_t)o;
            *(ushort4v*)((char*)Vm + vbyteoff) = st;
        }
    }
}

// ---------------------------------------------------------------------------
// Kernel 2: flash attention — R21 anchor (62.8us measured): 16 waves,
// quartered QK role, reg-staged V with T14 split, skewed P-exchange,
// bf16 O dump, setprio, __syncthreads barrier.
// ---------------------------------------------------------------------------
__global__ __launch_bounds__(1024, 4) void attn_kernel(
    const unsigned short* __restrict__ Qh, const unsigned short* __restrict__ Ql,
    const unsigned short* __restrict__ Kh, const unsigned short* __restrict__ Kl,
    const unsigned short* __restrict__ Vm,
    unsigned short* __restrict__ O_bf16, float* __restrict__ lsum_part)
{
    __shared__ __align__(16) char vlds[2][16384];   // V chunk double-buffer
    __shared__ __align__(16) char plds[2 * 8192];   // P exchange double-buffer

    int tid  = threadIdx.x;
    int wave = tid >> 6;          // 0..15
    int lane = tid & 63;
    int col = lane & 15, g = lane >> 4;
    int qq = wave >> 2;           // q-quarter 0..3
    int dq = wave & 3;            // d-quarter 0..3
    int kh = dq & 1;              // produced key-half
    int qs_own = dq >> 1;         // produced q-subtile
    int tid16 = tid * 16;
    int lane16 = lane * 16;

    int bid = blockIdx.x;
    int x7 = bid & 7;
    int b  = x7 >> 2;
    int ks = x7 & 3;
    int qt = bid >> 3;            // 0..31 (q-tile within batch)
    int q0 = qt * 128 + qq * 32;
    int jbase = ks * (N_ / 4);

    // Q fragments for OWN produced subtile only
    size_t qoff = ((size_t)b * N_ + q0 + qs_own * 16 + col) * C_ + g * 8;
    short8 qfh = *(const short8*)(Qh + qoff);
    short8 qfl = *(const short8*)(Ql + qoff);

    f32x4 acc[2][4];
#pragma unroll
    for (int qs = 0; qs < 2; ++qs)
#pragma unroll
        for (int dt = 0; dt < 4; ++dt) acc[qs][dt] = (f32x4){0.f, 0.f, 0.f, 0.f};
    float l_run = 0.f;

    const unsigned short* kbh = Kh + (size_t)b * N_ * C_;
    const unsigned short* kbl = Kl + (size_t)b * N_ * C_;
    const char* vbyte = (const char*)Vm + (size_t)b * ((size_t)N_ * D_ * 2);

    auto kaddr = [&](int it) {
        return (size_t)(jbase + it * 32 + kh * 16 + col) * C_ + g * 8;
    };

    // lane-constant swizzled ds_read offset for V fragments (d-quarter dq)
    unsigned vro = (unsigned)(((dq * 64 + col) * 64 + g * 16) ^ ((col & 7) << 4));
    int st = qq * 2 + qs_own;
    char* pmy = plds + st * 1024 + lane16 + kh * 8;       // own 8B publish slot
    const char* pr0 = plds + (qq * 2) * 1024 + lane16;     // subtile 0 read
    const char* pr1 = plds + (qq * 2 + 1) * 1024 + lane16; // subtile 1 read

    // ---- prologue: stage V(0); K(0)->A, K(1)->B; QK(0) -> plds buf0 ----
    {
        const char* vsrc = vbyte + (size_t)(ks * 32) * 16384 + tid16;
        *(f32x4*)(vlds[0] + tid16) = *(const f32x4*)(vsrc);
    }
    short8 khA = *(const short8*)(kbh + kaddr(0));
    short8 klA = *(const short8*)(kbl + kaddr(0));
    short8 khB = *(const short8*)(kbh + kaddr(1));
    short8 klB = *(const short8*)(kbl + kaddr(1));
    {
        f32x4 z = {0.f, 0.f, 0.f, 0.f};
        f32x4 sa = __builtin_amdgcn_mfma_f32_16x16x32_bf16(klA, qfh, z, 0, 0, 0);
        sa = __builtin_amdgcn_mfma_f32_16x16x32_bf16(khA, qfl, sa, 0, 0, 0);
        sa = __builtin_amdgcn_mfma_f32_16x16x32_bf16(khA, qfh, sa, 0, 0, 0);
        float pa[4];
#pragma unroll
        for (int r = 0; r < 4; ++r) pa[r] = exp2f(sa[r]);
        l_run += (pa[0] + pa[1]) + (pa[2] + pa[3]);
        uint2v uo;
        uo[0] = pk2(pa[0], pa[1]); uo[1] = pk2(pa[2], pa[3]);
        *(uint2v*)(pmy) = uo;   // buffer 0
    }
    __syncthreads();

    // phase IT: stage V(IT+1) (issue early / ds_write late), prefetch
    // K(IT+2), QK(IT+1) own quarter (CUR set), PV(IT) from plds/vlds[IT&1],
    // publish P+V, barrier.
#define ATTN_PHASE(IT, CKH, CKL, NKH, NKL)                                       \
    {                                                                            \
        int itn_ = (IT) + 1;                                                     \
        int itk_ = (IT) + 2;  /* may run past end: wrap-free, discarded */       \
        const char* vsrc_ = vbyte + (size_t)(ks * 32 + itn_) * 16384 + tid16;    \
        f32x4 stg_ = *(const f32x4*)(vsrc_);                                     \
        NKH = *(const short8*)(kbh + kaddr(itk_));                               \
        NKL = *(const short8*)(kbl + kaddr(itk_));                               \
        __builtin_amdgcn_sched_barrier(0);  /* loads stay issued up here */      \
        f32x4 z_ = {0.f, 0.f, 0.f, 0.f};                                         \
        __builtin_amdgcn_s_setprio(1);                                           \
        f32x4 sa_ = __builtin_amdgcn_mfma_f32_16x16x32_bf16(CKL, qfh, z_, 0, 0, 0); \
        sa_ = __builtin_amdgcn_mfma_f32_16x16x32_bf16(CKH, qfl, sa_, 0, 0, 0);   \
        sa_ = __builtin_amdgcn_mfma_f32_16x16x32_bf16(CKH, qfh, sa_, 0, 0, 0);   \
        __builtin_amdgcn_s_setprio(0);                                           \
        float pa_[4];                                                            \
        _Pragma("unroll")                                                        \
        for (int r = 0; r < 4; ++r) pa_[r] = exp2f(sa_[r]);                      \
        l_run += (pa_[0] + pa_[1]) + (pa_[2] + pa_[3]);                          \
        uint2v uo_;                                                              \
        uo_[0] = pk2(pa_[0], pa_[1]); uo_[1] = pk2(pa_[2], pa_[3]);              \
        int rb_ = (IT) & 1, wb_ = (itn_) & 1;                                    \
        short8 pf0_ = *(const short8*)(pr0 + rb_ * 8192);                        \
        short8 pf1_ = *(const short8*)(pr1 + rb_ * 8192);                        \
        short8 vf_[4];                                                           \
        _Pragma("unroll")                                                        \
        for (int dt = 0; dt < 4; ++dt)                                           \
            vf_[dt] = *(const short8*)(vlds[rb_] + vro + dt * 1024);             \
        __builtin_amdgcn_s_setprio(1);                                           \
        _Pragma("unroll")                                                        \
        for (int dt = 0; dt < 4; ++dt) {                                         \
            acc[0][dt] = __builtin_amdgcn_mfma_f32_16x16x32_bf16(vf_[dt], pf0_, acc[0][dt], 0, 0, 0); \
            acc[1][dt] = __builtin_amdgcn_mfma_f32_16x16x32_bf16(vf_[dt], pf1_, acc[1][dt], 0, 0, 0); \
        }                                                                        \
        __builtin_amdgcn_s_setprio(0);                                           \
        *(uint2v*)(pmy + wb_ * 8192) = uo_;                                      \
        *(f32x4*)(vlds[wb_] + tid16) = stg_;                                     \
        __syncthreads();                                                         \
    }

    for (int it2 = 0; it2 < 15; ++it2) {
        int itA = it2 * 2, itB = itA + 1;
        ATTN_PHASE(itA, khB, klB, khA, klA);
        ATTN_PHASE(itB, khA, klA, khB, klB);
    }
    ATTN_PHASE(30, khB, klB, khA, klA);
#undef ATTN_PHASE

    // epilogue: PV(31) from plds/vlds buffer 1
    {
        short8 pf0 = *(const short8*)(pr0 + 8192);
        short8 pf1 = *(const short8*)(pr1 + 8192);
        short8 vf[4];
#pragma unroll
        for (int dt = 0; dt < 4; ++dt)
            vf[dt] = *(const short8*)(vlds[1] + vro + dt * 1024);
#pragma unroll
        for (int dt = 0; dt < 4; ++dt) {
            acc[0][dt] = __builtin_amdgcn_mfma_f32_16x16x32_bf16(vf[dt], pf0, acc[0][dt], 0, 0, 0);
            acc[1][dt] = __builtin_amdgcn_mfma_f32_16x16x32_bf16(vf[dt], pf1, acc[1][dt], 0, 0, 0);
        }
    }

    // l reduction across the 4 g-groups (own subtile x own key-half)
    l_run += __shfl_xor(l_run, 16); l_run += __shfl_xor(l_run, 32);

    // dump partials as BF16, epi-compatible element layout: w = qq*2+(dq>>1),
    // j = qs*8 + (dq&1)*4 + dt, element = col*16 + g*4 (ushort units).
    unsigned short* op = O_bf16 + (size_t)bid * 32768 + (qq * 2 + (dq >> 1)) * 4096;
#pragma unroll
    for (int qs = 0; qs < 2; ++qs)
#pragma unroll
        for (int dt = 0; dt < 4; ++dt) {
            int j = qs * 8 + (dq & 1) * 4 + dt;
            uint2v uo;
            uo[0] = pk2(acc[qs][dt][0], acc[qs][dt][1]);
            uo[1] = pk2(acc[qs][dt][2], acc[qs][dt][3]);
            *(uint2v*)(op + j * 256 + col * 16 + g * 4) = uo;
        }
    if (g == 0)   // wave owns lsum slot (kh plane, qq, qs_own)
        lsum_part[bid * 256 + kh * 128 + qq * 32 + qs_own * 16 + col] = l_run;
}

// ---------------------------------------------------------------------------
// Kernel 3: epilogue. out[b,s,k,d] = gamma * (sum_ks O)/(sum_ks l) + x.
// O_part bf16 (same element-unit layout); l summed over kh planes.
// ---------------------------------------------------------------------------
__global__ __launch_bounds__(256) void epi_kernel(
    const unsigned short* __restrict__ O_bf16, const float* __restrict__ lsum_part,
    const float* __restrict__ x, const float* __restrict__ gamma_p,
    float* __restrict__ out)
{
    int gid = blockIdx.x * 256 + threadIdx.x;   // 0..524287
    int d  = (gid & 63) * 4;
    int nl = gid >> 6;
    int b  = nl >> 12;
    int n  = nl & (N_ - 1);

    int qt = n >> 7, qq = (n >> 5) & 3, qs = (n >> 4) & 1, col = n & 15;
    int dh = d >> 7, dt = (d >> 4) & 7;
    int w = qq * 2 + dh, j = qs * 8 + dt;
    int boff = w * 4096 + j * 256 + col * 16 + (d & 15);
    int loff = qq * 32 + qs * 16 + col;

    f32x4 acc = {0.f, 0.f, 0.f, 0.f};
    float l = 0.f;
#pragma unroll
    for (int ks = 0; ks < 4; ++ks) {
        int bid = qt * 8 + b * 4 + ks;
        ushort4v p = *(const ushort4v*)(O_bf16 + (size_t)bid * 32768 + boff);
        acc[0] += b2f(p[0]); acc[1] += b2f(p[1]);
        acc[2] += b2f(p[2]); acc[3] += b2f(p[3]);
        l += lsum_part[bid * 256 + loff] + lsum_part[bid * 256 + 128 + loff];
    }
    float scale = gamma_p[0] / l;
    int s = n & 63, kk = n >> 6;
    size_t o = (((size_t)(b * S_ + s)) * K_ + kk) * D_ + d;
    f32x4 xv = *(const f32x4*)(x + o);
    f32x4 ov;
#pragma unroll
    for (int e = 0; e < 4; ++e) ov[e] = acc[e] * scale + xv[e];
    *(f32x4*)(out + o) = ov;
}

extern "C" void kernel_launch(void* const* d_in, const int* in_sizes, int n_in,
                              void* d_out, int out_size, void* d_ws, size_t ws_size,
                              hipStream_t stream) {
    const float* x  = (const float*)d_in[0];
    const float* Wq = (const float*)d_in[1];
    const float* bq = (const float*)d_in[2];
    const float* Wk = (const float*)d_in[3];
    const float* bk = (const float*)d_in[4];
    const float* Wv = (const float*)d_in[5];
    const float* bv = (const float*)d_in[6];
    const float* gm = (const float*)d_in[7];

    char* ws = (char*)d_ws;
    unsigned short* Wh   = (unsigned short*)(ws);                 // 160KB
    unsigned short* Wl   = (unsigned short*)(ws + 0x40000);       // 160KB
    float*          bcat = (float*)         (ws + 0x80000);       // 1.3KB
    unsigned short* Qh   = (unsigned short*)(ws + 0x100000);      // 512KB
    unsigned short* Ql   = (unsigned short*)(ws + 0x180000);
    unsigned short* Kh   = (unsigned short*)(ws + 0x200000);
    unsigned short* Kl   = (unsigned short*)(ws + 0x280000);
    unsigned short* Vm   = (unsigned short*)(ws + 0x300000);      // 4MB
    unsigned short* Op   = (unsigned short*)(ws + 0x700000);      // 16MB (bf16)
    float*          lp   = (float*)         (ws + 0x2700000);     // 256KB
    float* o = (float*)d_out;

    wcvt_kernel<<<320, 256, 0, stream>>>(Wq, bq, Wk, bk, Wv, bv, Wh, Wl, bcat);
    qkv_kernel<<<512, 512, 0, stream>>>(x, Wh, Wl, bcat, Qh, Ql, Kh, Kl, Vm);
    attn_kernel<<<256, 1024, 0, stream>>>(Qh, Ql, Kh, Kl, Vm, Op, lp);
    epi_kernel<<<2048, 256, 0, stream>>>(Op, lp, x, gm, o);
}